// Round 25
// baseline (158.792 us; speedup 1.0000x reference)
//
#include <hip/hip_runtime.h>
#include <hip/hip_bf16.h>
#include <stdint.h>

#define B_ 4
#define T_ 2048
#define NH 16
#define DH 64
#define DIM 1024
#define NF 3072
#define QKS 2048   // qkF row stride (Q,K features only; V goes straight to Vt)

typedef unsigned short u16;
typedef uint32_t u32;
typedef __bf16 bf16;
typedef bf16 bf16x8 __attribute__((ext_vector_type(8)));
typedef float f32x4 __attribute__((ext_vector_type(4)));
typedef u16 u16x8 __attribute__((ext_vector_type(8)));
typedef u16 u16x4 __attribute__((ext_vector_type(4)));

__device__ __forceinline__ u16 f2bf(float f) {
    u32 u = __builtin_bit_cast(u32, f);
    u = (u + 0x7fffu + ((u >> 16) & 1u)) >> 16;
    return (u16)u;
}

__device__ __forceinline__ float exp2f_fast(float x) {
#if __has_builtin(__builtin_amdgcn_exp2f)
    return __builtin_amdgcn_exp2f(x);
#else
    return exp2f(x);
#endif
}

#define GLOAD16(g, l)                                                          \
    __builtin_amdgcn_global_load_lds(                                          \
        (const __attribute__((address_space(1))) u32*)(g),                     \
        (__attribute__((address_space(3))) u32*)(l), 16, 0, 0)

// ---------------- merged prep kernel ----------------
// bid <  3072 : W_qkv (DIMxNF) f32 -> WqkvT (N' x DIM) bf16, PERMUTED rows
//               n' = k*1024 + h*64 + d  (n = d*48 + k*16 + h)
// bid <  4096 : W0 (DIMxDIM) f32 -> W0T (DIM x DIM) bf16, plain transpose
// bid <  4352 : rel_bias -> rbT2 / rbT2s dual-parity bf16 tables, log2e-scaled,
//               causal mask folded (idx > 2047 -> -1e30)
// bid >= 4352 : x f32 -> xb bf16 (vectorized 8/thread; exact 8.4M elems)
__global__ __launch_bounds__(256) void prep_k(const float* __restrict__ x,
                                              const float* __restrict__ Wqkv,
                                              const float* __restrict__ W0,
                                              const float* __restrict__ rb,
                                              u16* __restrict__ xb,
                                              u16* __restrict__ WqkvT,
                                              u16* __restrict__ W0T,
                                              u16* __restrict__ rbT2,
                                              u16* __restrict__ rbT2s) {
    __shared__ float tile[32][33];
    const int bid = blockIdx.x;
    if (bid < 4096) {
        const bool perm = bid < 3072;
        const float* src = perm ? Wqkv : W0;
        u16* dst = perm ? WqkvT : W0T;
        const int N = perm ? NF : DIM;
        const int r2 = perm ? bid : bid - 3072;
        const int nb = perm ? 96 : 32;
        const int n0 = (r2 % nb) * 32, k0 = (r2 / nb) * 32;
        int c = threadIdx.x & 31, r0 = threadIdx.x >> 5;
#pragma unroll
        for (int i = 0; i < 4; i++) {
            int r = r0 + i * 8;
            tile[r][c] = src[(size_t)(k0 + r) * N + n0 + c];
        }
        __syncthreads();
#pragma unroll
        for (int i = 0; i < 4; i++) {
            int r = r0 + i * 8;
            int n = n0 + r;
            int nd;
            if (perm) {
                int d = n / 48, rem = n - d * 48;
                int kk = rem >> 4, h = rem & 15;
                nd = kk * 1024 + h * 64 + d;
            } else {
                nd = n;
            }
            dst[(size_t)nd * DIM + k0 + c] = f2bf(tile[c][r]);
        }
    } else if (bid < 4352) {
        int i = (bid - 4096) * 256 + threadIdx.x;   // 256 blocks cover NH*4096
        int h = i >> 12, d = i & 4095;
        float v = (d <= 2047) ? rb[(size_t)d * NH + h] * 1.44269504f : -1e30f;
        rbT2[i] = __builtin_bit_cast(u16, (bf16)v);
        int d2 = d + 1;
        float v2 = (d2 <= 2047) ? rb[(size_t)d2 * NH + h] * 1.44269504f : -1e30f;
        rbT2s[i] = __builtin_bit_cast(u16, (bf16)v2);
    } else {
        // x -> bf16: 4096 blocks x 256 threads x 8 elems = B*T*DIM exactly
        int i = (bid - 4352) * 256 + threadIdx.x;
        const float4* s = (const float4*)x + (size_t)i * 2;
        float4 a = s[0], b = s[1];
        u16x8 o;
        o[0]=f2bf(a.x); o[1]=f2bf(a.y); o[2]=f2bf(a.z); o[3]=f2bf(a.w);
        o[4]=f2bf(b.x); o[5]=f2bf(b.y); o[6]=f2bf(b.z); o[7]=f2bf(b.w);
        *(u16x8*)(xb + (size_t)i * 8) = o;
    }
}

// ---------------- GEMM: C = A(MxK) * Bt(NxK)^T, 128x128 tile, BK=64 ----------------
// OUTMODE 0: f32 C (out-proj). OUTMODE 1: merged QKV producer — bn<16 writes
// bf16 qkF (stride N=QKS); bn>=16 uses swapped MFMA operands so C'[n][m] has
// t on the lane axis and writes Vt[(b*16+h)*64+d][t] directly (coalesced).
// A is bf16 via global_load_lds (r20: f32 reg-staged A costs ~35 us).
// launch_bounds (256,2): (256,3) caps VGPR -> accumulator spills (r18).

template <int OUTMODE>
__global__ __launch_bounds__(256, 2) void gemm_bt_k(const u16* __restrict__ A,
                                                    const u16* __restrict__ Bt,
                                                    void* __restrict__ Cout,
                                                    u16* __restrict__ Vt,
                                                    int M, int N, int K) {
    __shared__ __align__(16) u16 As[128 * 64];
    __shared__ __align__(16) u16 Bs[128 * 64];
    const int tid = threadIdx.x;
    const int wave = tid >> 6, lane = tid & 63;
    const int bm = blockIdx.x, bn = blockIdx.y;
    const int wr = (wave >> 1) * 64, wc = (wave & 1) * 64;
    const int lrow = lane & 15, g4 = lane >> 4;
    const int srow8 = lane >> 3;           // 0..7 row within an 8-row gload
    const int scs = (lane & 7) ^ srow8;    // pre-swizzled source chunk
    const u16* Ab = A + (size_t)(bm * 128 + wave * 32) * K;
    const u16* Bb = Bt + (size_t)(bn * 128 + wave * 32) * K;
    u16* AsW = As + wave * 2048;           // wave rows [w*32, w*32+32), 64 k
    u16* BsW = Bs + wave * 2048;
    const bool vt = (OUTMODE == 1) && (bn >= 16);
    f32x4 acc[4][4] = {};

    for (int k0 = 0; k0 < K; k0 += 64) {
        __syncthreads();  // previous tile fully consumed
#pragma unroll
        for (int g = 0; g < 4; g++) {
            GLOAD16(Ab + (size_t)(g * 8 + srow8) * K + k0 + scs * 8, AsW + g * 512);
            GLOAD16(Bb + (size_t)(g * 8 + srow8) * K + k0 + scs * 8, BsW + g * 512);
        }
        __syncthreads();
#pragma unroll
        for (int kk2 = 0; kk2 < 2; kk2++) {
            bf16x8 af[4], bfr[4];
#pragma unroll
            for (int i = 0; i < 4; i++)
                af[i] = *(const bf16x8*)&As[(wr + i * 16 + lrow) * 64 +
                                            (((kk2 * 4 + g4) ^ (lrow & 7)) * 8)];
#pragma unroll
            for (int j = 0; j < 4; j++)
                bfr[j] = *(const bf16x8*)&Bs[(wc + j * 16 + lrow) * 64 +
                                             (((kk2 * 4 + g4) ^ (lrow & 7)) * 8)];
            if (vt) {
#pragma unroll
                for (int i = 0; i < 4; i++)
#pragma unroll
                    for (int j = 0; j < 4; j++)
                        acc[i][j] = __builtin_amdgcn_mfma_f32_16x16x32_bf16(
                            bfr[j], af[i], acc[i][j], 0, 0, 0);
            } else {
#pragma unroll
                for (int i = 0; i < 4; i++)
#pragma unroll
                    for (int j = 0; j < 4; j++)
                        acc[i][j] = __builtin_amdgcn_mfma_f32_16x16x32_bf16(
                            af[i], bfr[j], acc[i][j], 0, 0, 0);
            }
        }
    }

    const int crow = (lane >> 4) * 4, ccol = lane & 15;
    if (vt) {
        // C'[n][m]: lane col = m (t), rows = n (V feature f = h*64+d).
#pragma unroll
        for (int i = 0; i < 4; i++)
#pragma unroll
            for (int j = 0; j < 4; j++) {
                int gm = bm * 128 + wr + i * 16 + ccol;   // token index
                int b = gm >> 11, tt = gm & 2047;
#pragma unroll
                for (int r = 0; r < 4; r++) {
                    int f = (bn - 16) * 128 + wc + j * 16 + crow + r;  // h*64+d
                    int h = f >> 6, d = f & 63;
                    Vt[(((size_t)(b * NH + h)) * DH + d) * T_ + tt] =
                        f2bf(acc[i][j][r]);
                }
            }
    } else {
#pragma unroll
        for (int i = 0; i < 4; i++)
#pragma unroll
            for (int j = 0; j < 4; j++) {
                int gm = bm * 128 + wr + i * 16 + crow;
                int gn = bn * 128 + wc + j * 16 + ccol;
#pragma unroll
                for (int r = 0; r < 4; r++) {
                    if (OUTMODE == 1)
                        ((u16*)Cout)[(size_t)(gm + r) * N + gn] = f2bf(acc[i][j][r]);
                    else
                        ((float*)Cout)[(size_t)(gm + r) * N + gn] = acc[i][j][r];
                }
            }
    }
}

// ---------------- flash attention (swapped S' = K Q^T; 128-row q-tiles) ----------------
// r24 body (single K/V buffer, shared per-wave P buffer, 2-barrier inner
// loop, unpaired grid 1024 + LPT, XCD-local decode, LDS 40KB). ONLY change:
// __launch_bounds__(256, 4) — request 4 waves/EU so the runtime/allocator
// doesn't cap residency at 3 blocks/CU (r24: LDS allowed 4, got 3).
// VGPR 72 already fits the 4-block budget (128/wave).
__global__ __launch_bounds__(256, 4) void flash_attn_k(const u16* __restrict__ qkF,
                                                       const u16* __restrict__ Vt,
                                                       const u16* __restrict__ rbT2,
                                                       const u16* __restrict__ rbT2s,
                                                       u16* __restrict__ O) {
    __shared__ __align__(16) u16 Ks[64 * 64];
    __shared__ __align__(16) u16 Vs[64 * 64];
    __shared__ __align__(16) u16 Ps[4][16 * 64];
    __shared__ __align__(16) u16 rbs2a[4096];
    __shared__ __align__(16) u16 rbs2b[4096];
    const int tid = threadIdx.x, wave = tid >> 6, lane = tid & 63;
    const int Lid = blockIdx.x;
    const int c = Lid & 7, u = Lid >> 3;
    const int bh = ((u & 7) << 3) | c;     // bh%8 == c -> XCD-local K/V
    const int blk = 15 - (u >> 3);         // 128-row q-tile, longest-first (LPT)
    const int h = bh & 15, b = bh >> 4;
    const int l15 = lane & 15, g4 = lane >> 4;
    const float SC2 = 0.125f * 1.44269504f;  // scale * log2e

    {   // bias tables for this head (bf16, 4096-stride, 16B-aligned)
        *(u16x8*)&rbs2a[tid * 8] = *(const u16x8*)&rbT2[(size_t)h * 4096 + tid * 8];
        *(u16x8*)&rbs2a[2048 + tid * 8] = *(const u16x8*)&rbT2[(size_t)h * 4096 + 2048 + tid * 8];
        *(u16x8*)&rbs2b[tid * 8] = *(const u16x8*)&rbT2s[(size_t)h * 4096 + tid * 8];
        *(u16x8*)&rbs2b[2048 + tid * 8] = *(const u16x8*)&rbT2s[(size_t)h * 4096 + 2048 + tid * 8];
    }

    const size_t trow = (size_t)b * T_;
    u16* pw = &Ps[wave][0];
    // async staging geometry: wave w covers rows [16w, 16w+16) via 2 gloads
    // of 8 rows each; per-lane row = +lane>>3, chunk pos = lane&7, source
    // chunk = (lane&7)^(lane>>3) (pre-swizzled, rule #21).
    const int lrow8 = lane >> 3, lch = lane & 7;
    const int swz = lch ^ lrow8;
    // K slice rows: qkF[(b*T + t)*QKS + 1024 + h*64 + ...]
    const u16* kg0 = &qkF[(trow + wave * 16 + lrow8) * QKS + 1024 + h * 64 + swz * 8];
    const u16* kg1 = kg0 + (size_t)8 * QKS;
    const u16* vg0 = &Vt[((size_t)bh * DH + wave * 16 + lrow8) * T_ + swz * 8];
    const u16* vg1 = vg0 + (size_t)8 * T_;

#define STAGE_KV(j0n)                                                          \
    do {                                                                       \
        GLOAD16(kg0 + (size_t)(j0n) * QKS, &Ks[(wave * 16) * 64]);             \
        GLOAD16(kg1 + (size_t)(j0n) * QKS, &Ks[(wave * 16 + 8) * 64]);         \
        GLOAD16(vg0 + (j0n), &Vs[(wave * 16) * 64]);                           \
        GLOAD16(vg1 + (j0n), &Vs[(wave * 16 + 8) * 64]);                       \
    } while (0)

    const int qbA = blk * 128 + wave * 16;     // wave's first 16-row sub-block
    const int qbB = qbA + 64;                  // second sub-block
    bf16x8 aqA[2], aqB[2];
    aqA[0] = *(const bf16x8*)&qkF[(trow + qbA + l15) * QKS + h * 64 + g4 * 8];
    aqA[1] = *(const bf16x8*)&qkF[(trow + qbA + l15) * QKS + h * 64 + 32 + g4 * 8];
    aqB[0] = *(const bf16x8*)&qkF[(trow + qbB + l15) * QKS + h * 64 + g4 * 8];
    aqB[1] = *(const bf16x8*)&qkF[(trow + qbB + l15) * QKS + h * 64 + 32 + g4 * 8];

    // bias base for sub-block A (element index at j0=0, ni=0, r=0); >= 64.
    // Parity is identical for A and B (qbB = qbA + 64) -> one select.
    const int ibA = 2047 - l15 + g4 * 4 - qbA;
    const u32* b32A = (const u32*)((ibA & 1) ? &rbs2b[ibA - 1] : &rbs2a[ibA]);
    const u32* b32B = b32A - 32;   // shift by -64 elements = -32 u32

    f32x4 oaccA[4] = {}, oaccB[4] = {};
    float lA = 0.f, lB = 0.f;

    const int jtmax = 2 * blk + 1;
    for (int jt = 0; jt <= jtmax; jt++) {
        const int j0 = jt * 64;
        __syncthreads();   // previous tile fully consumed (covers rb on jt=0)
        STAGE_KV(j0);      // async-stage THIS tile
        __syncthreads();   // drains vmcnt -> tile resident
        // S' = K Q^T for both q-halves: each ak read feeds 2 MFMAs
        f32x4 sA[4], sB[4];
#pragma unroll
        for (int ni = 0; ni < 4; ni++) {
            f32x4 z = {};
            sA[ni] = z;
            sB[ni] = z;
        }
        __builtin_amdgcn_s_setprio(1);
#pragma unroll
        for (int ni = 0; ni < 4; ni++) {
            int arow = ni * 16 + l15;
#pragma unroll
            for (int kk = 0; kk < 2; kk++) {
                int ch = kk * 4 + g4;
                bf16x8 ak = *(const bf16x8*)&Ks[arow * 64 + ((ch ^ (arow & 7)) * 8)];
                sA[ni] = __builtin_amdgcn_mfma_f32_16x16x32_bf16(ak, aqA[kk], sA[ni], 0, 0, 0);
                sB[ni] = __builtin_amdgcn_mfma_f32_16x16x32_bf16(ak, aqB[kk], sB[ni], 0, 0, 0);
            }
        }
        __builtin_amdgcn_s_setprio(0);
        // softmax A (exp2 direct, no max-tracking) -> pw; hold bpA in regs
        const int jo = j0 >> 1;
        bf16x8 bpA[2], bpB[2];
        {
            float su = 0.f;
#pragma unroll
            for (int ni = 0; ni < 4; ni++) {
                u32 w0 = b32A[jo + ni * 8];
                u32 w1 = b32A[jo + ni * 8 + 1];
                float e0 = exp2f_fast(fmaf(sA[ni][0], SC2, __builtin_bit_cast(float, w0 << 16)));
                float e1 = exp2f_fast(fmaf(sA[ni][1], SC2, __builtin_bit_cast(float, w0 & 0xffff0000u)));
                float e2 = exp2f_fast(fmaf(sA[ni][2], SC2, __builtin_bit_cast(float, w1 << 16)));
                float e3 = exp2f_fast(fmaf(sA[ni][3], SC2, __builtin_bit_cast(float, w1 & 0xffff0000u)));
                su += (e0 + e1) + (e2 + e3);
                u16x4 pk;
                pk[0] = __builtin_bit_cast(u16, (bf16)e0);
                pk[1] = __builtin_bit_cast(u16, (bf16)e1);
                pk[2] = __builtin_bit_cast(u16, (bf16)e2);
                pk[3] = __builtin_bit_cast(u16, (bf16)e3);
                int colb = ni * 16 + g4 * 4;
                int ch = colb >> 3, co = colb & 7;
                *(u16x4*)&pw[l15 * 64 + ((ch ^ (l15 & 7)) * 8) + co] = pk;
            }
            su += __shfl_xor(su, 16);
            su += __shfl_xor(su, 32);
            lA += su;
            // read A's P-fragments BEFORE overwriting pw with B (same-wave
            // DS ops to the same buffer are program-ordered)
#pragma unroll
            for (int kk = 0; kk < 2; kk++) {
                int ch = kk * 4 + g4;
                bpA[kk] = *(const bf16x8*)&pw[l15 * 64 + ((ch ^ (l15 & 7)) * 8)];
            }
        }
        // softmax B -> pw (overwrite); read bpB
        {
            float su = 0.f;
#pragma unroll
            for (int ni = 0; ni < 4; ni++) {
                u32 w0 = b32B[jo + ni * 8];
                u32 w1 = b32B[jo + ni * 8 + 1];
                float e0 = exp2f_fast(fmaf(sB[ni][0], SC2, __builtin_bit_cast(float, w0 << 16)));
                float e1 = exp2f_fast(fmaf(sB[ni][1], SC2, __builtin_bit_cast(float, w0 & 0xffff0000u)));
                float e2 = exp2f_fast(fmaf(sB[ni][2], SC2, __builtin_bit_cast(float, w1 << 16)));
                float e3 = exp2f_fast(fmaf(sB[ni][3], SC2, __builtin_bit_cast(float, w1 & 0xffff0000u)));
                su += (e0 + e1) + (e2 + e3);
                u16x4 pk;
                pk[0] = __builtin_bit_cast(u16, (bf16)e0);
                pk[1] = __builtin_bit_cast(u16, (bf16)e1);
                pk[2] = __builtin_bit_cast(u16, (bf16)e2);
                pk[3] = __builtin_bit_cast(u16, (bf16)e3);
                int colb = ni * 16 + g4 * 4;
                int ch = colb >> 3, co = colb & 7;
                *(u16x4*)&pw[l15 * 64 + ((ch ^ (l15 & 7)) * 8) + co] = pk;
            }
            su += __shfl_xor(su, 16);
            su += __shfl_xor(su, 32);
            lB += su;
#pragma unroll
            for (int kk = 0; kk < 2; kk++) {
                int ch = kk * 4 + g4;
                bpB[kk] = *(const bf16x8*)&pw[l15 * 64 + ((ch ^ (l15 & 7)) * 8)];
            }
        }
        // PV: each av read feeds 2 MFMAs (both halves)
        __builtin_amdgcn_s_setprio(1);
#pragma unroll
        for (int di = 0; di < 4; di++) {
            int vrow = di * 16 + l15;
#pragma unroll
            for (int kk = 0; kk < 2; kk++) {
                int ch = kk * 4 + g4;
                bf16x8 av = *(const bf16x8*)&Vs[vrow * 64 + ((ch ^ (vrow & 7)) * 8)];
                oaccA[di] = __builtin_amdgcn_mfma_f32_16x16x32_bf16(av, bpA[kk], oaccA[di], 0, 0, 0);
                oaccB[di] = __builtin_amdgcn_mfma_f32_16x16x32_bf16(av, bpB[kk], oaccB[di], 0, 0, 0);
            }
        }
        __builtin_amdgcn_s_setprio(0);
    }
    // normalize + write attnO (b, t, h*64+d) bf16; lane owns q = qb?+l15,
    // d = di*16 + g4*4 + {0..3} -> 4x 8B stores per half
    {
        float inv = 1.0f / lA;
        u16* orow = &O[((size_t)b * T_ + qbA + l15) * (NH * DH) + h * DH];
#pragma unroll
        for (int di = 0; di < 4; di++) {
            u16x4 ov;
#pragma unroll
            for (int r = 0; r < 4; r++)
                ov[r] = __builtin_bit_cast(u16, (bf16)(oaccA[di][r] * inv));
            *(u16x4*)&orow[di * 16 + g4 * 4] = ov;
        }
    }
    {
        float inv = 1.0f / lB;
        u16* orow = &O[((size_t)b * T_ + qbB + l15) * (NH * DH) + h * DH];
#pragma unroll
        for (int di = 0; di < 4; di++) {
            u16x4 ov;
#pragma unroll
            for (int r = 0; r < 4; r++)
                ov[r] = __builtin_bit_cast(u16, (bf16)(oaccB[di][r] * inv));
            *(u16x4*)&orow[di * 16 + g4 * 4] = ov;
        }
    }
#undef STAGE_KV
}

// ---------------- launcher ----------------

extern "C" void kernel_launch(void* const* d_in, const int* in_sizes, int n_in,
                              void* d_out, int out_size, void* d_ws, size_t ws_size,
                              hipStream_t stream) {
    const float* x    = (const float*)d_in[0];
    const float* Wqkv = (const float*)d_in[1];
    const float* W0   = (const float*)d_in[2];
    const float* rb   = (const float*)d_in[3];
    char* ws = (char*)d_ws;

    // ws layout (bytes); qkF live through flash; no aliasing
    u16*   xb    = (u16*)(ws + 0);            // 16,777,216
    u16*   WqkvT = (u16*)(ws + 16777216);     //  6,291,456
    u16*   W0T   = (u16*)(ws + 23068672);     //  2,097,152
    u16*   rbT2  = (u16*)(ws + 25165824);     //    131,072 (16 x 4096 bf16)
    u16*   rbT2s = (u16*)(ws + 25296896);     //    131,072 (shifted copy)
    u16*   qkF   = (u16*)(ws + 25427968);     // 33,554,432 (Q,K features, stride 2048)
    u16*   attnO = (u16*)(ws + 58982400);     // 16,777,216
    u16*   Vtb   = (u16*)(ws + 75759616);     // 16,777,216 -> total 92,536,832

    // merged prep: WqkvT (permuted) + W0T + bias tables + x->bf16, one dispatch
    prep_k<<<8448, 256, 0, stream>>>(x, Wqkv, W0, rb, xb, WqkvT, W0T, rbT2, rbT2s);

    // merged QKV GEMM: bn<16 -> qkF[b*T+t][k*1024+h*64+d]; bn>=16 -> Vt direct
    gemm_bt_k<1><<<dim3((B_ * T_) / 128, NF / 128), 256, 0, stream>>>(
        xb, WqkvT, qkF, Vtb, B_ * T_, QKS, DIM);

    flash_attn_k<<<1024, 256, 0, stream>>>(qkF, Vtb, rbT2, rbT2s, attnO);

    gemm_bt_k<0><<<dim3((B_ * T_) / 128, DIM / 128), 256, 0, stream>>>(
        attnO, W0T, d_out, nullptr, B_ * T_, DIM, DIM);
}

// Round 26
// 155.751 us; speedup vs baseline: 1.0195x; 1.0195x over previous
//
#include <hip/hip_runtime.h>
#include <hip/hip_bf16.h>
#include <stdint.h>

#define B_ 4
#define T_ 2048
#define NH 16
#define DH 64
#define DIM 1024
#define NF 3072
#define QKS 2048   // qkF row stride (Q,K features only; V goes straight to Vt)

typedef unsigned short u16;
typedef uint32_t u32;
typedef __bf16 bf16;
typedef bf16 bf16x8 __attribute__((ext_vector_type(8)));
typedef float f32x4 __attribute__((ext_vector_type(4)));
typedef u16 u16x8 __attribute__((ext_vector_type(8)));
typedef u16 u16x4 __attribute__((ext_vector_type(4)));

__device__ __forceinline__ u16 f2bf(float f) {
    u32 u = __builtin_bit_cast(u32, f);
    u = (u + 0x7fffu + ((u >> 16) & 1u)) >> 16;
    return (u16)u;
}

__device__ __forceinline__ float exp2f_fast(float x) {
#if __has_builtin(__builtin_amdgcn_exp2f)
    return __builtin_amdgcn_exp2f(x);
#else
    return exp2f(x);
#endif
}

#define GLOAD16(g, l)                                                          \
    __builtin_amdgcn_global_load_lds(                                          \
        (const __attribute__((address_space(1))) u32*)(g),                     \
        (__attribute__((address_space(3))) u32*)(l), 16, 0, 0)

// ---------------- merged prep kernel ----------------
// bid <  3072 : W_qkv (DIMxNF) f32 -> WqkvT (N' x DIM) bf16, PERMUTED rows
//               n' = k*1024 + h*64 + d  (n = d*48 + k*16 + h)
// bid <  4096 : W0 (DIMxDIM) f32 -> W0T (DIM x DIM) bf16, plain transpose
// bid <  4352 : rel_bias -> rbT2 / rbT2s dual-parity bf16 tables, log2e-scaled,
//               causal mask folded (idx > 2047 -> -1e30)
// bid >= 4352 : x f32 -> xb bf16 (vectorized 8/thread; exact 8.4M elems)
__global__ __launch_bounds__(256) void prep_k(const float* __restrict__ x,
                                              const float* __restrict__ Wqkv,
                                              const float* __restrict__ W0,
                                              const float* __restrict__ rb,
                                              u16* __restrict__ xb,
                                              u16* __restrict__ WqkvT,
                                              u16* __restrict__ W0T,
                                              u16* __restrict__ rbT2,
                                              u16* __restrict__ rbT2s) {
    __shared__ float tile[32][33];
    const int bid = blockIdx.x;
    if (bid < 4096) {
        const bool perm = bid < 3072;
        const float* src = perm ? Wqkv : W0;
        u16* dst = perm ? WqkvT : W0T;
        const int N = perm ? NF : DIM;
        const int r2 = perm ? bid : bid - 3072;
        const int nb = perm ? 96 : 32;
        const int n0 = (r2 % nb) * 32, k0 = (r2 / nb) * 32;
        int c = threadIdx.x & 31, r0 = threadIdx.x >> 5;
#pragma unroll
        for (int i = 0; i < 4; i++) {
            int r = r0 + i * 8;
            tile[r][c] = src[(size_t)(k0 + r) * N + n0 + c];
        }
        __syncthreads();
#pragma unroll
        for (int i = 0; i < 4; i++) {
            int r = r0 + i * 8;
            int n = n0 + r;
            int nd;
            if (perm) {
                int d = n / 48, rem = n - d * 48;
                int kk = rem >> 4, h = rem & 15;
                nd = kk * 1024 + h * 64 + d;
            } else {
                nd = n;
            }
            dst[(size_t)nd * DIM + k0 + c] = f2bf(tile[c][r]);
        }
    } else if (bid < 4352) {
        int i = (bid - 4096) * 256 + threadIdx.x;   // 256 blocks cover NH*4096
        int h = i >> 12, d = i & 4095;
        float v = (d <= 2047) ? rb[(size_t)d * NH + h] * 1.44269504f : -1e30f;
        rbT2[i] = __builtin_bit_cast(u16, (bf16)v);
        int d2 = d + 1;
        float v2 = (d2 <= 2047) ? rb[(size_t)d2 * NH + h] * 1.44269504f : -1e30f;
        rbT2s[i] = __builtin_bit_cast(u16, (bf16)v2);
    } else {
        // x -> bf16: 4096 blocks x 256 threads x 8 elems = B*T*DIM exactly
        int i = (bid - 4352) * 256 + threadIdx.x;
        const float4* s = (const float4*)x + (size_t)i * 2;
        float4 a = s[0], b = s[1];
        u16x8 o;
        o[0]=f2bf(a.x); o[1]=f2bf(a.y); o[2]=f2bf(a.z); o[3]=f2bf(a.w);
        o[4]=f2bf(b.x); o[5]=f2bf(b.y); o[6]=f2bf(b.z); o[7]=f2bf(b.w);
        *(u16x8*)(xb + (size_t)i * 8) = o;
    }
}

// ---------------- GEMM: C = A(MxK) * Bt(NxK)^T, 128x128 tile, BK=64 ----------------
// OUTMODE 0: f32 C (out-proj). OUTMODE 1: merged QKV producer — bn<16 writes
// bf16 qkF (stride N=QKS); bn>=16 uses swapped MFMA operands so C'[n][m] has
// t on the lane axis and writes Vt[(b*16+h)*64+d][t] directly (coalesced).
// A is bf16 via global_load_lds (r20: f32 reg-staged A costs ~35 us).
// launch_bounds (256,2): (256,3) caps VGPR -> accumulator spills (r18).

template <int OUTMODE>
__global__ __launch_bounds__(256, 2) void gemm_bt_k(const u16* __restrict__ A,
                                                    const u16* __restrict__ Bt,
                                                    void* __restrict__ Cout,
                                                    u16* __restrict__ Vt,
                                                    int M, int N, int K) {
    __shared__ __align__(16) u16 As[128 * 64];
    __shared__ __align__(16) u16 Bs[128 * 64];
    const int tid = threadIdx.x;
    const int wave = tid >> 6, lane = tid & 63;
    const int bm = blockIdx.x, bn = blockIdx.y;
    const int wr = (wave >> 1) * 64, wc = (wave & 1) * 64;
    const int lrow = lane & 15, g4 = lane >> 4;
    const int srow8 = lane >> 3;           // 0..7 row within an 8-row gload
    const int scs = (lane & 7) ^ srow8;    // pre-swizzled source chunk
    const u16* Ab = A + (size_t)(bm * 128 + wave * 32) * K;
    const u16* Bb = Bt + (size_t)(bn * 128 + wave * 32) * K;
    u16* AsW = As + wave * 2048;           // wave rows [w*32, w*32+32), 64 k
    u16* BsW = Bs + wave * 2048;
    const bool vt = (OUTMODE == 1) && (bn >= 16);
    f32x4 acc[4][4] = {};

    for (int k0 = 0; k0 < K; k0 += 64) {
        __syncthreads();  // previous tile fully consumed
#pragma unroll
        for (int g = 0; g < 4; g++) {
            GLOAD16(Ab + (size_t)(g * 8 + srow8) * K + k0 + scs * 8, AsW + g * 512);
            GLOAD16(Bb + (size_t)(g * 8 + srow8) * K + k0 + scs * 8, BsW + g * 512);
        }
        __syncthreads();
#pragma unroll
        for (int kk2 = 0; kk2 < 2; kk2++) {
            bf16x8 af[4], bfr[4];
#pragma unroll
            for (int i = 0; i < 4; i++)
                af[i] = *(const bf16x8*)&As[(wr + i * 16 + lrow) * 64 +
                                            (((kk2 * 4 + g4) ^ (lrow & 7)) * 8)];
#pragma unroll
            for (int j = 0; j < 4; j++)
                bfr[j] = *(const bf16x8*)&Bs[(wc + j * 16 + lrow) * 64 +
                                             (((kk2 * 4 + g4) ^ (lrow & 7)) * 8)];
            if (vt) {
#pragma unroll
                for (int i = 0; i < 4; i++)
#pragma unroll
                    for (int j = 0; j < 4; j++)
                        acc[i][j] = __builtin_amdgcn_mfma_f32_16x16x32_bf16(
                            bfr[j], af[i], acc[i][j], 0, 0, 0);
            } else {
#pragma unroll
                for (int i = 0; i < 4; i++)
#pragma unroll
                    for (int j = 0; j < 4; j++)
                        acc[i][j] = __builtin_amdgcn_mfma_f32_16x16x32_bf16(
                            af[i], bfr[j], acc[i][j], 0, 0, 0);
            }
        }
    }

    const int crow = (lane >> 4) * 4, ccol = lane & 15;
    if (vt) {
        // C'[n][m]: lane col = m (t), rows = n (V feature f = h*64+d).
#pragma unroll
        for (int i = 0; i < 4; i++)
#pragma unroll
            for (int j = 0; j < 4; j++) {
                int gm = bm * 128 + wr + i * 16 + ccol;   // token index
                int b = gm >> 11, tt = gm & 2047;
#pragma unroll
                for (int r = 0; r < 4; r++) {
                    int f = (bn - 16) * 128 + wc + j * 16 + crow + r;  // h*64+d
                    int h = f >> 6, d = f & 63;
                    Vt[(((size_t)(b * NH + h)) * DH + d) * T_ + tt] =
                        f2bf(acc[i][j][r]);
                }
            }
    } else {
#pragma unroll
        for (int i = 0; i < 4; i++)
#pragma unroll
            for (int j = 0; j < 4; j++) {
                int gm = bm * 128 + wr + i * 16 + crow;
                int gn = bn * 128 + wc + j * 16 + ccol;
#pragma unroll
                for (int r = 0; r < 4; r++) {
                    if (OUTMODE == 1)
                        ((u16*)Cout)[(size_t)(gm + r) * N + gn] = f2bf(acc[i][j][r]);
                    else
                        ((float*)Cout)[(size_t)(gm + r) * N + gn] = acc[i][j][r];
                }
            }
    }
}

// ---------------- flash attention (swapped S' = K Q^T; 128-row q-tiles) ----------------
// r24 proven kernel (68.5 us): single K/V buffer, shared per-wave P buffer
// (halves A/B time-share it; same-wave DS ops program-ordered), 2-barrier
// m97 inner loop with async global_load_lds staging, unpaired grid 1024 +
// LPT (longest-first), XCD-local decode, dual-parity bf16 bias tables,
// exp2 no-max softmax, swizzle both-sides (rule #21). LDS 40KB.
// launch_bounds (256,2): (256,4) trims VGPR 72->64 and spills (r25).
__global__ __launch_bounds__(256, 2) void flash_attn_k(const u16* __restrict__ qkF,
                                                       const u16* __restrict__ Vt,
                                                       const u16* __restrict__ rbT2,
                                                       const u16* __restrict__ rbT2s,
                                                       u16* __restrict__ O) {
    __shared__ __align__(16) u16 Ks[64 * 64];
    __shared__ __align__(16) u16 Vs[64 * 64];
    __shared__ __align__(16) u16 Ps[4][16 * 64];
    __shared__ __align__(16) u16 rbs2a[4096];
    __shared__ __align__(16) u16 rbs2b[4096];
    const int tid = threadIdx.x, wave = tid >> 6, lane = tid & 63;
    const int Lid = blockIdx.x;
    const int c = Lid & 7, u = Lid >> 3;
    const int bh = ((u & 7) << 3) | c;     // bh%8 == c -> XCD-local K/V
    const int blk = 15 - (u >> 3);         // 128-row q-tile, longest-first (LPT)
    const int h = bh & 15, b = bh >> 4;
    const int l15 = lane & 15, g4 = lane >> 4;
    const float SC2 = 0.125f * 1.44269504f;  // scale * log2e

    {   // bias tables for this head (bf16, 4096-stride, 16B-aligned)
        *(u16x8*)&rbs2a[tid * 8] = *(const u16x8*)&rbT2[(size_t)h * 4096 + tid * 8];
        *(u16x8*)&rbs2a[2048 + tid * 8] = *(const u16x8*)&rbT2[(size_t)h * 4096 + 2048 + tid * 8];
        *(u16x8*)&rbs2b[tid * 8] = *(const u16x8*)&rbT2s[(size_t)h * 4096 + tid * 8];
        *(u16x8*)&rbs2b[2048 + tid * 8] = *(const u16x8*)&rbT2s[(size_t)h * 4096 + 2048 + tid * 8];
    }

    const size_t trow = (size_t)b * T_;
    u16* pw = &Ps[wave][0];
    // async staging geometry: wave w covers rows [16w, 16w+16) via 2 gloads
    // of 8 rows each; per-lane row = +lane>>3, chunk pos = lane&7, source
    // chunk = (lane&7)^(lane>>3) (pre-swizzled, rule #21).
    const int lrow8 = lane >> 3, lch = lane & 7;
    const int swz = lch ^ lrow8;
    // K slice rows: qkF[(b*T + t)*QKS + 1024 + h*64 + ...]
    const u16* kg0 = &qkF[(trow + wave * 16 + lrow8) * QKS + 1024 + h * 64 + swz * 8];
    const u16* kg1 = kg0 + (size_t)8 * QKS;
    const u16* vg0 = &Vt[((size_t)bh * DH + wave * 16 + lrow8) * T_ + swz * 8];
    const u16* vg1 = vg0 + (size_t)8 * T_;

#define STAGE_KV(j0n)                                                          \
    do {                                                                       \
        GLOAD16(kg0 + (size_t)(j0n) * QKS, &Ks[(wave * 16) * 64]);             \
        GLOAD16(kg1 + (size_t)(j0n) * QKS, &Ks[(wave * 16 + 8) * 64]);         \
        GLOAD16(vg0 + (j0n), &Vs[(wave * 16) * 64]);                           \
        GLOAD16(vg1 + (j0n), &Vs[(wave * 16 + 8) * 64]);                       \
    } while (0)

    const int qbA = blk * 128 + wave * 16;     // wave's first 16-row sub-block
    const int qbB = qbA + 64;                  // second sub-block
    bf16x8 aqA[2], aqB[2];
    aqA[0] = *(const bf16x8*)&qkF[(trow + qbA + l15) * QKS + h * 64 + g4 * 8];
    aqA[1] = *(const bf16x8*)&qkF[(trow + qbA + l15) * QKS + h * 64 + 32 + g4 * 8];
    aqB[0] = *(const bf16x8*)&qkF[(trow + qbB + l15) * QKS + h * 64 + g4 * 8];
    aqB[1] = *(const bf16x8*)&qkF[(trow + qbB + l15) * QKS + h * 64 + 32 + g4 * 8];

    // bias base for sub-block A (element index at j0=0, ni=0, r=0); >= 64.
    // Parity is identical for A and B (qbB = qbA + 64) -> one select.
    const int ibA = 2047 - l15 + g4 * 4 - qbA;
    const u32* b32A = (const u32*)((ibA & 1) ? &rbs2b[ibA - 1] : &rbs2a[ibA]);
    const u32* b32B = b32A - 32;   // shift by -64 elements = -32 u32

    f32x4 oaccA[4] = {}, oaccB[4] = {};
    float lA = 0.f, lB = 0.f;

    const int jtmax = 2 * blk + 1;
    for (int jt = 0; jt <= jtmax; jt++) {
        const int j0 = jt * 64;
        __syncthreads();   // previous tile fully consumed (covers rb on jt=0)
        STAGE_KV(j0);      // async-stage THIS tile
        __syncthreads();   // drains vmcnt -> tile resident
        // S' = K Q^T for both q-halves: each ak read feeds 2 MFMAs
        f32x4 sA[4], sB[4];
#pragma unroll
        for (int ni = 0; ni < 4; ni++) {
            f32x4 z = {};
            sA[ni] = z;
            sB[ni] = z;
        }
        __builtin_amdgcn_s_setprio(1);
#pragma unroll
        for (int ni = 0; ni < 4; ni++) {
            int arow = ni * 16 + l15;
#pragma unroll
            for (int kk = 0; kk < 2; kk++) {
                int ch = kk * 4 + g4;
                bf16x8 ak = *(const bf16x8*)&Ks[arow * 64 + ((ch ^ (arow & 7)) * 8)];
                sA[ni] = __builtin_amdgcn_mfma_f32_16x16x32_bf16(ak, aqA[kk], sA[ni], 0, 0, 0);
                sB[ni] = __builtin_amdgcn_mfma_f32_16x16x32_bf16(ak, aqB[kk], sB[ni], 0, 0, 0);
            }
        }
        __builtin_amdgcn_s_setprio(0);
        // softmax A (exp2 direct, no max-tracking) -> pw; hold bpA in regs
        const int jo = j0 >> 1;
        bf16x8 bpA[2], bpB[2];
        {
            float su = 0.f;
#pragma unroll
            for (int ni = 0; ni < 4; ni++) {
                u32 w0 = b32A[jo + ni * 8];
                u32 w1 = b32A[jo + ni * 8 + 1];
                float e0 = exp2f_fast(fmaf(sA[ni][0], SC2, __builtin_bit_cast(float, w0 << 16)));
                float e1 = exp2f_fast(fmaf(sA[ni][1], SC2, __builtin_bit_cast(float, w0 & 0xffff0000u)));
                float e2 = exp2f_fast(fmaf(sA[ni][2], SC2, __builtin_bit_cast(float, w1 << 16)));
                float e3 = exp2f_fast(fmaf(sA[ni][3], SC2, __builtin_bit_cast(float, w1 & 0xffff0000u)));
                su += (e0 + e1) + (e2 + e3);
                u16x4 pk;
                pk[0] = __builtin_bit_cast(u16, (bf16)e0);
                pk[1] = __builtin_bit_cast(u16, (bf16)e1);
                pk[2] = __builtin_bit_cast(u16, (bf16)e2);
                pk[3] = __builtin_bit_cast(u16, (bf16)e3);
                int colb = ni * 16 + g4 * 4;
                int ch = colb >> 3, co = colb & 7;
                *(u16x4*)&pw[l15 * 64 + ((ch ^ (l15 & 7)) * 8) + co] = pk;
            }
            su += __shfl_xor(su, 16);
            su += __shfl_xor(su, 32);
            lA += su;
            // read A's P-fragments BEFORE overwriting pw with B (same-wave
            // DS ops to the same buffer are program-ordered)
#pragma unroll
            for (int kk = 0; kk < 2; kk++) {
                int ch = kk * 4 + g4;
                bpA[kk] = *(const bf16x8*)&pw[l15 * 64 + ((ch ^ (l15 & 7)) * 8)];
            }
        }
        // softmax B -> pw (overwrite); read bpB
        {
            float su = 0.f;
#pragma unroll
            for (int ni = 0; ni < 4; ni++) {
                u32 w0 = b32B[jo + ni * 8];
                u32 w1 = b32B[jo + ni * 8 + 1];
                float e0 = exp2f_fast(fmaf(sB[ni][0], SC2, __builtin_bit_cast(float, w0 << 16)));
                float e1 = exp2f_fast(fmaf(sB[ni][1], SC2, __builtin_bit_cast(float, w0 & 0xffff0000u)));
                float e2 = exp2f_fast(fmaf(sB[ni][2], SC2, __builtin_bit_cast(float, w1 << 16)));
                float e3 = exp2f_fast(fmaf(sB[ni][3], SC2, __builtin_bit_cast(float, w1 & 0xffff0000u)));
                su += (e0 + e1) + (e2 + e3);
                u16x4 pk;
                pk[0] = __builtin_bit_cast(u16, (bf16)e0);
                pk[1] = __builtin_bit_cast(u16, (bf16)e1);
                pk[2] = __builtin_bit_cast(u16, (bf16)e2);
                pk[3] = __builtin_bit_cast(u16, (bf16)e3);
                int colb = ni * 16 + g4 * 4;
                int ch = colb >> 3, co = colb & 7;
                *(u16x4*)&pw[l15 * 64 + ((ch ^ (l15 & 7)) * 8) + co] = pk;
            }
            su += __shfl_xor(su, 16);
            su += __shfl_xor(su, 32);
            lB += su;
#pragma unroll
            for (int kk = 0; kk < 2; kk++) {
                int ch = kk * 4 + g4;
                bpB[kk] = *(const bf16x8*)&pw[l15 * 64 + ((ch ^ (l15 & 7)) * 8)];
            }
        }
        // PV: each av read feeds 2 MFMAs (both halves)
        __builtin_amdgcn_s_setprio(1);
#pragma unroll
        for (int di = 0; di < 4; di++) {
            int vrow = di * 16 + l15;
#pragma unroll
            for (int kk = 0; kk < 2; kk++) {
                int ch = kk * 4 + g4;
                bf16x8 av = *(const bf16x8*)&Vs[vrow * 64 + ((ch ^ (vrow & 7)) * 8)];
                oaccA[di] = __builtin_amdgcn_mfma_f32_16x16x32_bf16(av, bpA[kk], oaccA[di], 0, 0, 0);
                oaccB[di] = __builtin_amdgcn_mfma_f32_16x16x32_bf16(av, bpB[kk], oaccB[di], 0, 0, 0);
            }
        }
        __builtin_amdgcn_s_setprio(0);
    }
    // normalize + write attnO (b, t, h*64+d) bf16; lane owns q = qb?+l15,
    // d = di*16 + g4*4 + {0..3} -> 4x 8B stores per half
    {
        float inv = 1.0f / lA;
        u16* orow = &O[((size_t)b * T_ + qbA + l15) * (NH * DH) + h * DH];
#pragma unroll
        for (int di = 0; di < 4; di++) {
            u16x4 ov;
#pragma unroll
            for (int r = 0; r < 4; r++)
                ov[r] = __builtin_bit_cast(u16, (bf16)(oaccA[di][r] * inv));
            *(u16x4*)&orow[di * 16 + g4 * 4] = ov;
        }
    }
    {
        float inv = 1.0f / lB;
        u16* orow = &O[((size_t)b * T_ + qbB + l15) * (NH * DH) + h * DH];
#pragma unroll
        for (int di = 0; di < 4; di++) {
            u16x4 ov;
#pragma unroll
            for (int r = 0; r < 4; r++)
                ov[r] = __builtin_bit_cast(u16, (bf16)(oaccB[di][r] * inv));
            *(u16x4*)&orow[di * 16 + g4 * 4] = ov;
        }
    }
#undef STAGE_KV
}

// ---------------- launcher ----------------

extern "C" void kernel_launch(void* const* d_in, const int* in_sizes, int n_in,
                              void* d_out, int out_size, void* d_ws, size_t ws_size,
                              hipStream_t stream) {
    const float* x    = (const float*)d_in[0];
    const float* Wqkv = (const float*)d_in[1];
    const float* W0   = (const float*)d_in[2];
    const float* rb   = (const float*)d_in[3];
    char* ws = (char*)d_ws;

    // ws layout (bytes); qkF live through flash; no aliasing
    u16*   xb    = (u16*)(ws + 0);            // 16,777,216
    u16*   WqkvT = (u16*)(ws + 16777216);     //  6,291,456
    u16*   W0T   = (u16*)(ws + 23068672);     //  2,097,152
    u16*   rbT2  = (u16*)(ws + 25165824);     //    131,072 (16 x 4096 bf16)
    u16*   rbT2s = (u16*)(ws + 25296896);     //    131,072 (shifted copy)
    u16*   qkF   = (u16*)(ws + 25427968);     // 33,554,432 (Q,K features, stride 2048)
    u16*   attnO = (u16*)(ws + 58982400);     // 16,777,216
    u16*   Vtb   = (u16*)(ws + 75759616);     // 16,777,216 -> total 92,536,832

    // merged prep: WqkvT (permuted) + W0T + bias tables + x->bf16, one dispatch
    prep_k<<<8448, 256, 0, stream>>>(x, Wqkv, W0, rb, xb, WqkvT, W0T, rbT2, rbT2s);

    // merged QKV GEMM: bn<16 -> qkF[b*T+t][k*1024+h*64+d]; bn>=16 -> Vt direct
    gemm_bt_k<1><<<dim3((B_ * T_) / 128, NF / 128), 256, 0, stream>>>(
        xb, WqkvT, qkF, Vtb, B_ * T_, QKS, DIM);

    flash_attn_k<<<1024, 256, 0, stream>>>(qkF, Vtb, rbT2, rbT2s, attnO);

    gemm_bt_k<0><<<dim3((B_ * T_) / 128, DIM / 128), 256, 0, stream>>>(
        attnO, W0T, d_out, nullptr, B_ * T_, DIM, DIM);
}